// Round 10
// baseline (759.738 us; speedup 1.0000x reference)
//
#include <hip/hip_runtime.h>

#define B_ 512
#define H_ 512

typedef short short8 __attribute__((ext_vector_type(8)));
typedef float f32x4 __attribute__((ext_vector_type(4)));

__device__ __forceinline__ unsigned short bf16rne(float f) {
  unsigned u = __float_as_uint(f);
  u += 0x7FFFu + ((u >> 16) & 1u);
  return (unsigned short)(u >> 16);
}

// Fused prep (blocks 0..255, 4 rows each) + W2 pack (blocks 256..2303).
// pack layout (shorts): d = gt*65536 + c*4096 + plane*2048 + nf*512 + ks*128
//                           + g15*8 + e
//   g = gt*64 + nf*16 + g15,  k = c*32 + ks*8 + e
// -> per (gt,c): 8 KB contiguous; lane's frag slice = base + lane*8.
__global__ __launch_bounds__(256) void k_pre(const float* __restrict__ x,
                                             const float* __restrict__ y,
                                             const float* __restrict__ W1,
                                             const float* __restrict__ b1,
                                             const float* __restrict__ W2,
                                             float* __restrict__ hx,
                                             float* __restrict__ hy,
                                             unsigned short* __restrict__ w2p) {
  __shared__ float xs[4][128];
  const int blk = blockIdx.x;
  const int t = threadIdx.x;
  if (blk < 256) {
    const bool isx = blk < 128;
    const int r0 = (isx ? blk : blk - 128) * 4;  // 4 rows per block
    const float* src = (isx ? x : y) + r0 * 128;
    if (t < 128) ((float4*)xs)[t] = ((const float4*)src)[t];
    __syncthreads();
    const int woff = isx ? 0 : 128;
    float* dst = (isx ? hx : hy) + r0 * H_;
#pragma unroll
    for (int hh = 0; hh < 2; ++hh) {
      const int h = t + hh * 256;
      const float4* wr = (const float4*)(W1 + h * 256 + woff);
      float a0 = isx ? b1[h] : 0.f, a1 = a0, a2 = a0, a3 = a0;
#pragma unroll
      for (int n = 0; n < 32; ++n) {
        float4 w = wr[n];
        float4 v0 = ((const float4*)xs[0])[n];
        float4 v1 = ((const float4*)xs[1])[n];
        float4 v2 = ((const float4*)xs[2])[n];
        float4 v3 = ((const float4*)xs[3])[n];
        a0 = fmaf(w.x, v0.x, fmaf(w.y, v0.y, fmaf(w.z, v0.z, fmaf(w.w, v0.w, a0))));
        a1 = fmaf(w.x, v1.x, fmaf(w.y, v1.y, fmaf(w.z, v1.z, fmaf(w.w, v1.w, a1))));
        a2 = fmaf(w.x, v2.x, fmaf(w.y, v2.y, fmaf(w.z, v2.z, fmaf(w.w, v2.w, a2))));
        a3 = fmaf(w.x, v3.x, fmaf(w.y, v3.y, fmaf(w.z, v3.z, fmaf(w.w, v3.w, a3))));
      }
      dst[h] = a0;
      dst[H_ + h] = a1;
      dst[2 * H_ + h] = a2;
      dst[3 * H_ + h] = a3;
    }
  } else {
    int d = (blk - 256) * 256 + t;  // 0..524287
    int e = d & 7;
    int g15 = (d >> 3) & 15;
    int ks = (d >> 7) & 3;
    int nf = (d >> 9) & 3;
    int plane = (d >> 11) & 1;
    int c = (d >> 12) & 15;
    int gt = d >> 16;
    int g = gt * 64 + nf * 16 + g15;
    int k = c * 32 + ks * 8 + e;
    float v = W2[g * H_ + k];
    unsigned short h = bf16rne(v);
    float r = v - __uint_as_float(((unsigned)h) << 16);
    w2p[d] = plane ? bf16rne(r) : h;
  }
}

// add + relu + chop-to-bf16 of 2 elems -> one packed u32 (5 VALU)
__device__ __forceinline__ unsigned chop2(float x0, float x1, float y0,
                                          float y1) {
  float t0 = fmaxf(x0 + y0, 0.f);
  float t1 = fmaxf(x1 + y1, 0.f);
  return __builtin_amdgcn_perm(__float_as_uint(t1), __float_as_uint(t0),
                               0x07060302);  // {hi16(t0), hi16(t1)}
}

// Barrier-free fused middle layer. Wave = independent tile: 64 pairs
// (4 i x 16 j) x 64 g (4 nf). B private per wave, loaded straight to
// registers from the packed stream (no duplication across waves), A built
// in registers (chop bf16, single plane), D += A*Bl + A*Bh.
// No LDS, no __syncthreads -> issue ports pack across resident waves (m114).
__global__ __launch_bounds__(256, 3) void k_main(
    const float* __restrict__ hx, const float* __restrict__ hy,
    const unsigned short* __restrict__ w2p,
    const float* __restrict__ b2, const float* __restrict__ w3,
    const float* __restrict__ b3, float* __restrict__ out) {
  const int tid = threadIdx.x;
  const int lane = tid & 63;
  const int wid = tid >> 6;  // 0..3

  const int wv = blockIdx.x * 4 + wid;  // 0..32767
  const int pt = wv >> 3;               // pair-tile 0..4095 (block: same pt)
  const int gt = wv & 7;                // g-tile (64 wide)
  const int ibase = (pt >> 5) << 2;     // i tiled by 4
  const int jbase = (pt & 31) << 4;     // j tiled by 16
  const int l15 = lane & 15;
  const int kslot = (lane >> 4) << 3;   // 0,8,16,24

  const float* hxp = hx + (jbase + l15) * H_ + kslot;
  const float* hyp = hy + ibase * H_ + kslot;  // 4 rows, stride H_

  const unsigned short* bp0 = w2p + gt * 65536 + lane * 8;  // hi plane
  const unsigned short* bp1 = bp0 + 2048;                   // lo plane

  f32x4 acc[4][4] = {};

  // chunk-0 A inputs
  float4 X0 = *(const float4*)(hxp);
  float4 X1 = *(const float4*)(hxp + 4);
  float4 Ya[4], Yb[4];
#pragma unroll
  for (int mf = 0; mf < 4; ++mf) {
    Ya[mf] = *(const float4*)(hyp + mf * H_);
    Yb[mf] = *(const float4*)(hyp + mf * H_ + 4);
  }

#pragma unroll 1
  for (int c = 0; c < 16; ++c) {
    // issue this chunk's B loads first; latency hides under the build
    const unsigned short* b0 = bp0 + c * 4096;
    const unsigned short* b1 = bp1 + c * 4096;
    short8 Bh[4], Bl[4];
#pragma unroll
    for (int nf = 0; nf < 4; ++nf) {
      Bh[nf] = *(const short8*)(b0 + nf * 512);
      Bl[nf] = *(const short8*)(b1 + nf * 512);
    }
    // build A frags(c) from inputs already in registers
    union { unsigned u[4]; short8 s; } A[4];
#pragma unroll
    for (int mf = 0; mf < 4; ++mf) {
      A[mf].u[0] = chop2(X0.x, X0.y, Ya[mf].x, Ya[mf].y);
      A[mf].u[1] = chop2(X0.z, X0.w, Ya[mf].z, Ya[mf].w);
      A[mf].u[2] = chop2(X1.x, X1.y, Yb[mf].x, Yb[mf].y);
      A[mf].u[3] = chop2(X1.z, X1.w, Yb[mf].z, Yb[mf].w);
    }
    // prefetch next chunk's A inputs (consumed next iteration)
    if (c < 15) {
      const int ko = (c + 1) * 32;
      X0 = *(const float4*)(hxp + ko);
      X1 = *(const float4*)(hxp + ko + 4);
#pragma unroll
      for (int mf = 0; mf < 4; ++mf) {
        Ya[mf] = *(const float4*)(hyp + mf * H_ + ko);
        Yb[mf] = *(const float4*)(hyp + mf * H_ + ko + 4);
      }
    }
    // MFMA: 4 nf x 4 mf x 2 planes = 32
#pragma unroll
    for (int nf = 0; nf < 4; ++nf) {
      __builtin_amdgcn_s_setprio(1);
#pragma unroll
      for (int mf = 0; mf < 4; ++mf) {
        f32x4 a = acc[mf][nf];
        a = __builtin_amdgcn_mfma_f32_16x16x32_bf16(A[mf].s, Bl[nf], a, 0, 0, 0);
        a = __builtin_amdgcn_mfma_f32_16x16x32_bf16(A[mf].s, Bh[nf], a, 0, 0, 0);
        acc[mf][nf] = a;
      }
      __builtin_amdgcn_s_setprio(0);
    }
  }

  // epilogue: relu(acc+b2) dot w3, shfl-reduce over 16 g-lanes, atomic out
  const int gbase = gt << 6;
  float b2v[4], w3v[4];
#pragma unroll
  for (int nf = 0; nf < 4; ++nf) {
    int g = gbase + nf * 16 + l15;
    b2v[nf] = b2[g];
    w3v[nf] = w3[g];
  }
  const float b3v = (gt == 0) ? b3[0] : 0.f;
#pragma unroll
  for (int mf = 0; mf < 4; ++mf) {
#pragma unroll
    for (int r = 0; r < 4; ++r) {
      float s = 0.f;
#pragma unroll
      for (int nf = 0; nf < 4; ++nf) {
        // C/D layout (m89/m91): col = lane&15 (g), row = (lane>>4)*4 + r (j_l)
        float h2 = fmaxf(acc[mf][nf][r] + b2v[nf], 0.f);
        s = fmaf(w3v[nf], h2, s);
      }
      s += __shfl_xor(s, 1);
      s += __shfl_xor(s, 2);
      s += __shfl_xor(s, 4);
      s += __shfl_xor(s, 8);
      if (l15 == 0) {
        int jl = ((lane >> 4) << 2) + r;
        atomicAdd(out + (ibase + mf) * B_ + jbase + jl, s + b3v);
      }
    }
  }
}

extern "C" void kernel_launch(void* const* d_in, const int* in_sizes, int n_in,
                              void* d_out, int out_size, void* d_ws, size_t ws_size,
                              hipStream_t stream) {
  const float* x  = (const float*)d_in[0];
  const float* y  = (const float*)d_in[1];
  const float* W1 = (const float*)d_in[2];
  const float* b1 = (const float*)d_in[3];
  const float* W2 = (const float*)d_in[4];
  const float* b2 = (const float*)d_in[5];
  const float* W3 = (const float*)d_in[6];
  const float* b3 = (const float*)d_in[7];
  float* out = (float*)d_out;

  char* ws = (char*)d_ws;
  float* hx = (float*)ws;                                   // 1 MB
  float* hy = (float*)(ws + (1u << 20));                    // 1 MB
  unsigned short* w2p = (unsigned short*)(ws + (2u << 20)); // 1 MB packed hi/lo

  hipMemsetAsync(d_out, 0, (size_t)out_size * sizeof(float), stream);
  k_pre<<<2304, 256, 0, stream>>>(x, y, W1, b1, W2, hx, hy, w2p);
  k_main<<<8192, 256, 0, stream>>>(hx, hy, w2p, b2, W3, b3, out);
}

// Round 11
// 302.613 us; speedup vs baseline: 2.5106x; 2.5106x over previous
//
#include <hip/hip_runtime.h>

#define B_ 512
#define H_ 512

typedef short short8 __attribute__((ext_vector_type(8)));
typedef float f32x4 __attribute__((ext_vector_type(4)));

__device__ __forceinline__ unsigned short bf16rne(float f) {
  unsigned u = __float_as_uint(f);
  u += 0x7FFFu + ((u >> 16) & 1u);
  return (unsigned short)(u >> 16);
}

// Fused prep (blocks 0..255, 4 rows each) + W2 pack (blocks 256..2303).
// prep: hx[j][h] = x[j]·W1[h,:128] + b1[h]; hy[i][h] = y[i]·W1[h,128:]
// pack: w2p[d], d = nt*131072 + c*8192 + plane*4096 + nf*512 + ks*128 + g15*8 + e
//   g = nt*128+nf*16+g15, k = c*32+ks*8+e; chunk = 16 KB contiguous.
__global__ __launch_bounds__(256) void k_pre(const float* __restrict__ x,
                                             const float* __restrict__ y,
                                             const float* __restrict__ W1,
                                             const float* __restrict__ b1,
                                             const float* __restrict__ W2,
                                             float* __restrict__ hx,
                                             float* __restrict__ hy,
                                             unsigned short* __restrict__ w2p) {
  __shared__ float xs[4][128];
  const int blk = blockIdx.x;
  const int t = threadIdx.x;
  if (blk < 256) {
    const bool isx = blk < 128;
    const int r0 = (isx ? blk : blk - 128) * 4;  // 4 rows per block
    const float* src = (isx ? x : y) + r0 * 128;
    if (t < 128) ((float4*)xs)[t] = ((const float4*)src)[t];
    __syncthreads();
    const int woff = isx ? 0 : 128;
    float* dst = (isx ? hx : hy) + r0 * H_;
#pragma unroll
    for (int hh = 0; hh < 2; ++hh) {
      const int h = t + hh * 256;
      const float4* wr = (const float4*)(W1 + h * 256 + woff);
      float a0 = isx ? b1[h] : 0.f, a1 = a0, a2 = a0, a3 = a0;
#pragma unroll
      for (int n = 0; n < 32; ++n) {
        float4 w = wr[n];
        float4 v0 = ((const float4*)xs[0])[n];
        float4 v1 = ((const float4*)xs[1])[n];
        float4 v2 = ((const float4*)xs[2])[n];
        float4 v3 = ((const float4*)xs[3])[n];
        a0 = fmaf(w.x, v0.x, fmaf(w.y, v0.y, fmaf(w.z, v0.z, fmaf(w.w, v0.w, a0))));
        a1 = fmaf(w.x, v1.x, fmaf(w.y, v1.y, fmaf(w.z, v1.z, fmaf(w.w, v1.w, a1))));
        a2 = fmaf(w.x, v2.x, fmaf(w.y, v2.y, fmaf(w.z, v2.z, fmaf(w.w, v2.w, a2))));
        a3 = fmaf(w.x, v3.x, fmaf(w.y, v3.y, fmaf(w.z, v3.z, fmaf(w.w, v3.w, a3))));
      }
      dst[h] = a0;
      dst[H_ + h] = a1;
      dst[2 * H_ + h] = a2;
      dst[3 * H_ + h] = a3;
    }
  } else {
    int d = (blk - 256) * 256 + t;  // 0..524287
    int e = d & 7;
    int g15 = (d >> 3) & 15;
    int ks = (d >> 7) & 3;
    int nf = (d >> 9) & 7;
    int plane = (d >> 12) & 1;
    int c = (d >> 13) & 15;
    int nt = (d >> 17) & 3;
    int g = nt * 128 + nf * 16 + g15;
    int k = c * 32 + ks * 8 + e;
    float v = W2[g * H_ + k];
    unsigned short h = bf16rne(v);
    float r = v - __uint_as_float(((unsigned)h) << 16);
    w2p[d] = plane ? bf16rne(r) : h;
  }
}

// add + relu + chop-to-bf16 of 2 elems -> one packed u32 (5 VALU)
__device__ __forceinline__ unsigned chop2(float x0, float x1, float y0,
                                          float y1) {
  float t0 = fmaxf(x0 + y0, 0.f);
  float t1 = fmaxf(x1 + y1, 0.f);
  return __builtin_amdgcn_perm(__float_as_uint(t1), __float_as_uint(t0),
                               0x07060302);  // {hi16(t0), hi16(t1)}
}

union Frag { unsigned u[4]; short8 s; };

// build frag m of NXT from next-chunk inputs (4 chop2)
#define BUILD_FRAG(NXT, m_)                                                   \
  {                                                                           \
    NXT[m_].u[0] = chop2(X0.x, X0.y, Ya[m_].x, Ya[m_].y);                     \
    NXT[m_].u[1] = chop2(X0.z, X0.w, Ya[m_].z, Ya[m_].w);                     \
    NXT[m_].u[2] = chop2(X1.x, X1.y, Yb[m_].x, Yb[m_].y);                     \
    NXT[m_].u[3] = chop2(X1.z, X1.w, Yb[m_].z, Yb[m_].w);                     \
  }

// One K-chunk: 64 MFMA (4 mf x 8 nf x 2 planes) from CUR; STAGE(c+1);
// prefetch A-inputs(c+1); build NXT sliced into nf>=4; one barrier at end.
#define CHUNK_STEP(c_, buf_, CUR, NXT)                                        \
  {                                                                           \
    if ((c_) < 15) STAGE((c_) + 1, (buf_) ^ 1);                               \
    const int ko_ = ((c_) + 1) * 32;                                          \
    X0 = *(const float4*)(hxp + ko_);                                         \
    X1 = *(const float4*)(hxp + ko_ + 4);                                     \
    _Pragma("unroll") for (int m = 0; m < 4; ++m) {                           \
      Ya[m] = *(const float4*)(hyp + m * H_ + ko_);                           \
      Yb[m] = *(const float4*)(hyp + m * H_ + ko_ + 4);                       \
    }                                                                         \
    const unsigned short* bb_ = (buf_) ? bbr1 : bbr0;                         \
    _Pragma("unroll") for (int nf = 0; nf < 8; ++nf) {                        \
      short8 Bh = *(const short8*)(bb_ + nf * 512);                           \
      short8 Bl = *(const short8*)(bb_ + 4096 + nf * 512);                    \
      __builtin_amdgcn_s_setprio(1);                                          \
      _Pragma("unroll") for (int m = 0; m < 4; ++m) {                         \
        f32x4 a = acc[m][nf];                                                 \
        a = __builtin_amdgcn_mfma_f32_16x16x32_bf16(CUR[m].s, Bl, a, 0, 0, 0);\
        a = __builtin_amdgcn_mfma_f32_16x16x32_bf16(CUR[m].s, Bh, a, 0, 0, 0);\
        acc[m][nf] = a;                                                       \
      }                                                                       \
      __builtin_amdgcn_s_setprio(0);                                          \
      if ((nf) >= 4) BUILD_FRAG(NXT, (nf) - 4);                               \
    }                                                                         \
    __syncthreads();                                                          \
  }

// Fused middle layer: register-built A (chop bf16, 4 i-rows per wave) +
// LDS-staged split-B (double-buffered global_load_lds). Block = 256 thr
// (4 waves), tile 256 pairs (16 i x 16 j) x 128 g. 64 MFMA per barrier:
// fixed per-chunk costs (stage, barrier drain, ds_reads) amortized 2x vs R8.
__global__ __launch_bounds__(256, 2) void k_main(
    const float* __restrict__ hx, const float* __restrict__ hy,
    const unsigned short* __restrict__ w2p,
    const float* __restrict__ b2, const float* __restrict__ w3,
    const float* __restrict__ b3, float* __restrict__ out) {
  __shared__ alignas(16) unsigned short Bs[2][8192];  // 2 x 16 KB

  const int tid = threadIdx.x;
  const int lane = tid & 63;
  const int wid = tid >> 6;  // 0..3

  const int bid = blockIdx.x;
  const int ntile = bid & 3;
  const int mtile = bid >> 2;           // 0..1023
  const int ibase = (mtile >> 5) << 4;  // i tiled by 16
  const int jbase = (mtile & 31) << 4;  // j tiled by 16
  const int l15 = lane & 15;
  const int kslot = (lane >> 4) << 3;   // 0,8,16,24

  const float* hxp = hx + (jbase + l15) * H_ + kslot;
  const float* hyp = hy + (ibase + wid * 4) * H_ + kslot;  // 4 rows, stride H_

  const unsigned short* gstage = w2p + ntile * 131072 + wid * 2048 + lane * 8;
  unsigned short* lds_dst0 = &Bs[0][wid * 2048];
  unsigned short* lds_dst1 = &Bs[1][wid * 2048];
  const unsigned short* bbr0 = &Bs[0][0] + lane * 8;
  const unsigned short* bbr1 = &Bs[1][0] + lane * 8;

  auto STAGE = [&](int c, int buf) {
    const unsigned short* g = gstage + c * 8192;
    unsigned short* l = buf ? lds_dst1 : lds_dst0;
#pragma unroll
    for (int q = 0; q < 4; ++q) {
      __builtin_amdgcn_global_load_lds(
          (const __attribute__((address_space(1))) unsigned int*)(g + q * 512),
          (__attribute__((address_space(3))) unsigned int*)(l + q * 512),
          16, 0, 0);
    }
  };

  f32x4 acc[4][8] = {};
  Frag F[4], G[4];
  float4 X0, X1, Ya[4], Yb[4];

  // prologue: stage chunk 0, build F from chunk-0 inputs
  STAGE(0, 0);
  X0 = *(const float4*)(hxp);
  X1 = *(const float4*)(hxp + 4);
#pragma unroll
  for (int m = 0; m < 4; ++m) {
    Ya[m] = *(const float4*)(hyp + m * H_);
    Yb[m] = *(const float4*)(hyp + m * H_ + 4);
  }
#pragma unroll
  for (int m = 0; m < 4; ++m) BUILD_FRAG(F, m);
  __syncthreads();

  for (int cc = 0; cc < 8; ++cc) {
    CHUNK_STEP(2 * cc, 0, F, G);
    CHUNK_STEP(2 * cc + 1, 1, G, F);
  }

  // epilogue: relu(acc+b2) dot w3, shfl-reduce over 16 g-lanes, atomic out
  const int gbase = ntile << 7;
  float b2v[8], w3v[8];
#pragma unroll
  for (int nf = 0; nf < 8; ++nf) {
    int g = gbase + nf * 16 + l15;
    b2v[nf] = b2[g];
    w3v[nf] = w3[g];
  }
  const float b3v = (ntile == 0) ? b3[0] : 0.f;
#pragma unroll
  for (int mf = 0; mf < 4; ++mf) {
#pragma unroll
    for (int r = 0; r < 4; ++r) {
      float s = 0.f;
#pragma unroll
      for (int nf = 0; nf < 8; ++nf) {
        // C/D layout (m89/m91): col = lane&15 (g), row = (lane>>4)*4 + r (j_l)
        float h2 = fmaxf(acc[mf][nf][r] + b2v[nf], 0.f);
        s = fmaf(w3v[nf], h2, s);
      }
      s += __shfl_xor(s, 1);
      s += __shfl_xor(s, 2);
      s += __shfl_xor(s, 4);
      s += __shfl_xor(s, 8);
      if (l15 == 0) {
        int jl = ((lane >> 4) << 2) + r;
        int il = wid * 4 + mf;
        atomicAdd(out + (ibase + il) * B_ + jbase + jl, s + b3v);
      }
    }
  }
}

extern "C" void kernel_launch(void* const* d_in, const int* in_sizes, int n_in,
                              void* d_out, int out_size, void* d_ws, size_t ws_size,
                              hipStream_t stream) {
  const float* x  = (const float*)d_in[0];
  const float* y  = (const float*)d_in[1];
  const float* W1 = (const float*)d_in[2];
  const float* b1 = (const float*)d_in[3];
  const float* W2 = (const float*)d_in[4];
  const float* b2 = (const float*)d_in[5];
  const float* W3 = (const float*)d_in[6];
  const float* b3 = (const float*)d_in[7];
  float* out = (float*)d_out;

  char* ws = (char*)d_ws;
  float* hx = (float*)ws;                                   // 1 MB
  float* hy = (float*)(ws + (1u << 20));                    // 1 MB
  unsigned short* w2p = (unsigned short*)(ws + (2u << 20)); // 1 MB packed hi/lo

  hipMemsetAsync(d_out, 0, (size_t)out_size * sizeof(float), stream);
  k_pre<<<2304, 256, 0, stream>>>(x, y, W1, b1, W2, hx, hy, w2p);
  k_main<<<4096, 256, 0, stream>>>(hx, hy, w2p, b2, W3, b3, out);
}